// Round 1
// baseline (438.395 us; speedup 1.0000x reference)
//
#include <hip/hip_runtime.h>
#include <stdint.h>

// Pipeline:
//  K1: w[h][i][j]   = softmax_j( LN(z[i,j,:]) . W_b[h,:] + INF*(z_mask-1) )   (bf16)
//  K2: vT[h][s*32+c][j] = (LN(m[s,j,:]) . W_v[h*32+c,:]) * msa_mask[s,j]      (bf16)
//      g[s][i][hc]      = sigmoid(LN(m[s,i,:]) . W_g[hc,:])                    (bf16)
//  K3: O[h][i][s*32+c]  = sum_j w[h][i][j] * vT[h][s*32+c][j]                  (f32)
//  K4: out[s][i][cm]    = sum_hc (g[s][i][hc]*O[h][i][s*32+c]) * W_o[cm][hc]   (f32)

typedef unsigned short u16;
typedef unsigned int u32;
typedef __attribute__((ext_vector_type(4))) float f32x4;
typedef __attribute__((ext_vector_type(8))) short bf16x8;

#define INF8 1e8f

__device__ __forceinline__ u16 f2bf(float f) {
  u32 u = __float_as_uint(f);
  u = u + 0x7fffu + ((u >> 16) & 1u);
  return (u16)(u >> 16);
}
__device__ __forceinline__ float bf2f(u16 h) {
  return __uint_as_float(((u32)h) << 16);
}

#define GLD_LDS16(gp, lp) __builtin_amdgcn_global_load_lds(                 \
    (__attribute__((address_space(1))) const void*)(gp),                    \
    (__attribute__((address_space(3))) void*)(lp), 16, 0, 0)

// ---------------------------------------------------------------- Kernel 1
__global__ __launch_bounds__(256) void k1_bias_softmax(
    const float* __restrict__ z, const float* __restrict__ z_mask,
    const float* __restrict__ gzp, const float* __restrict__ bzp,
    const float* __restrict__ W_b, u16* __restrict__ w_out)
{
  const int i = blockIdx.x;      // 0..511
  const int t = threadIdx.x;     // 0..255
  __shared__ float zn[32][133];  // padded: conflict-free column reads
  __shared__ float bl[8][512];
  __shared__ float wb[8][128];
  __shared__ float gz[128], bz[128];
  for (int idx = t; idx < 1024; idx += 256) wb[idx >> 7][idx & 127] = W_b[idx];
  if (t < 128) { gz[t] = gzp[t]; bz[t] = bzp[t]; }
  __syncthreads();

  const int jl = t >> 3;    // row in chunk (0..31)
  const int part = t & 7;   // 8 threads per row
  const int h = t >> 5, jj = t & 31;

  for (int chunk = 0; chunk < 16; ++chunk) {
    const float* zrow = z + ((size_t)i * 512 + chunk * 32 + jl) * 128;
    f32x4 v[4];
    float s = 0.f, sq = 0.f;
#pragma unroll
    for (int q = 0; q < 4; ++q) {
      v[q] = *reinterpret_cast<const f32x4*>(zrow + 4 * (part + 8 * q));
#pragma unroll
      for (int e = 0; e < 4; ++e) { s += v[q][e]; sq += v[q][e] * v[q][e]; }
    }
#pragma unroll
    for (int msk = 1; msk < 8; msk <<= 1) {
      s += __shfl_xor(s, msk, 8);
      sq += __shfl_xor(sq, msk, 8);
    }
    float mean = s * (1.f / 128.f);
    float rstd = rsqrtf(sq * (1.f / 128.f) - mean * mean + 1e-5f);
#pragma unroll
    for (int q = 0; q < 4; ++q) {
      int k0 = 4 * (part + 8 * q);
#pragma unroll
      for (int e = 0; e < 4; ++e) {
        int k = k0 + e;
        zn[jl][k] = (v[q][e] - mean) * rstd * gz[k] + bz[k];
      }
    }
    __syncthreads();
    // b for 32 j's x 8 heads
    {
      float acc = 0.f;
#pragma unroll 8
      for (int k = 0; k < 128; ++k) acc += zn[jj][k] * wb[h][k];
      float zm = z_mask[(size_t)i * 512 + chunk * 32 + jj];
      bl[h][chunk * 32 + jj] = acc + INF8 * (zm - 1.f);
    }
    __syncthreads();
  }
  // softmax over j (512) for each h; 32 lanes per h
  {
    const int l = t & 31;
    float vals[16];
    float mx = -3.4e38f;
#pragma unroll
    for (int q = 0; q < 16; ++q) { vals[q] = bl[h][l + 32 * q]; mx = fmaxf(mx, vals[q]); }
#pragma unroll
    for (int msk = 1; msk < 32; msk <<= 1) mx = fmaxf(mx, __shfl_xor(mx, msk, 32));
    float sum = 0.f;
#pragma unroll
    for (int q = 0; q < 16; ++q) { vals[q] = __expf(vals[q] - mx); sum += vals[q]; }
#pragma unroll
    for (int msk = 1; msk < 32; msk <<= 1) sum += __shfl_xor(sum, msk, 32);
    float inv = 1.f / sum;
    u16* wrow = w_out + ((size_t)h * 512 + i) * 512;
#pragma unroll
    for (int q = 0; q < 16; ++q) wrow[l + 32 * q] = f2bf(vals[q] * inv);
  }
}

// ---------------------------------------------------------------- Kernel 2
// grid (4, 256): jt, s. Block 256 = 4 waves.
// waves 0,1 -> W_v rows [0,128)/[128,256); waves 2,3 -> W_g likewise.
__global__ __launch_bounds__(256) void k2_vg(
    const float* __restrict__ m, const float* __restrict__ msa_mask,
    const float* __restrict__ gmp, const float* __restrict__ bmp,
    const float* __restrict__ W_v, const float* __restrict__ W_g,
    u16* __restrict__ vT, u16* __restrict__ g_out)
{
  const int jt = blockIdx.x, s = blockIdx.y;
  const int j0 = jt * 128;
  const int t = threadIdx.x;
  const int lane = t & 63, wid = t >> 6;
  __shared__ u16 bt[128][80];     // m_ln tile, rows=j (128), K=64, pad to 80
  __shared__ float gk[64], bk[64];
  if (t < 64) { gk[t] = gmp[t]; bk[t] = bmp[t]; }
  __syncthreads();

  // Phase A: LayerNorm of 128 m-rows -> bf16 LDS (one thread per row)
  if (t < 128) {
    const float* mrow = m + ((size_t)s * 512 + j0 + t) * 64;
    f32x4 v[16];
    float s1 = 0.f, s2 = 0.f;
#pragma unroll
    for (int q = 0; q < 16; ++q) {
      v[q] = *reinterpret_cast<const f32x4*>(mrow + 4 * q);
#pragma unroll
      for (int e = 0; e < 4; ++e) { s1 += v[q][e]; s2 += v[q][e] * v[q][e]; }
    }
    float mean = s1 * (1.f / 64.f);
    float rstd = rsqrtf(s2 * (1.f / 64.f) - mean * mean + 1e-5f);
#pragma unroll
    for (int q = 0; q < 16; ++q) {
      int k0 = q * 4;
      u32 p0 = (u32)f2bf((v[q][0] - mean) * rstd * gk[k0]     + bk[k0])
             | ((u32)f2bf((v[q][1] - mean) * rstd * gk[k0 + 1] + bk[k0 + 1]) << 16);
      u32 p1 = (u32)f2bf((v[q][2] - mean) * rstd * gk[k0 + 2] + bk[k0 + 2])
             | ((u32)f2bf((v[q][3] - mean) * rstd * gk[k0 + 3] + bk[k0 + 3]) << 16);
      *reinterpret_cast<u32*>(&bt[t][k0]) = p0;
      *reinterpret_cast<u32*>(&bt[t][k0 + 2]) = p1;
    }
  }

  // Phase B: per-wave A fragments (W rows) from global, kept in registers
  const float* Wsrc = (wid < 2) ? W_v : W_g;
  const int row0 = (wid & 1) * 128;
  const int r16 = lane & 15, kg = lane >> 4;
  bf16x8 afrag[8][2];
#pragma unroll
  for (int mf = 0; mf < 8; ++mf) {
    int row = row0 + mf * 16 + r16;
#pragma unroll
    for (int kf = 0; kf < 2; ++kf) {
      int k = kf * 32 + kg * 8;
      f32x4 x0 = *reinterpret_cast<const f32x4*>(Wsrc + row * 64 + k);
      f32x4 x1 = *reinterpret_cast<const f32x4*>(Wsrc + row * 64 + k + 4);
      bf16x8 a;
      a[0] = (short)f2bf(x0[0]); a[1] = (short)f2bf(x0[1]);
      a[2] = (short)f2bf(x0[2]); a[3] = (short)f2bf(x0[3]);
      a[4] = (short)f2bf(x1[0]); a[5] = (short)f2bf(x1[1]);
      a[6] = (short)f2bf(x1[2]); a[7] = (short)f2bf(x1[3]);
      afrag[mf][kf] = a;
    }
  }
  __syncthreads();

  // Phase C: MFMA, N in chunks of 16 cols
  for (int nc = 0; nc < 8; ++nc) {
    bf16x8 b0 = *reinterpret_cast<const bf16x8*>(&bt[nc * 16 + r16][kg * 8]);
    bf16x8 b1 = *reinterpret_cast<const bf16x8*>(&bt[nc * 16 + r16][32 + kg * 8]);
    f32x4 acc[8];
#pragma unroll
    for (int mf = 0; mf < 8; ++mf) acc[mf] = (f32x4){0.f, 0.f, 0.f, 0.f};
#pragma unroll
    for (int mf = 0; mf < 8; ++mf) {
      acc[mf] = __builtin_amdgcn_mfma_f32_16x16x32_bf16(afrag[mf][0], b0, acc[mf], 0, 0, 0);
      acc[mf] = __builtin_amdgcn_mfma_f32_16x16x32_bf16(afrag[mf][1], b1, acc[mf], 0, 0, 0);
    }
    const int colj = j0 + nc * 16 + r16;
    if (wid < 2) {
      float mask = msa_mask[(size_t)s * 512 + colj];
#pragma unroll
      for (int mf = 0; mf < 8; ++mf) {
#pragma unroll
        for (int r = 0; r < 4; ++r) {
          int hcrow = row0 + mf * 16 + kg * 4 + r;
          int hh = hcrow >> 5, cc = hcrow & 31;
          vT[((size_t)hh * 8192 + s * 32 + cc) * 512 + colj] = f2bf(acc[mf][r] * mask);
        }
      }
    } else {
#pragma unroll
      for (int mf = 0; mf < 8; ++mf) {
        int hcrow0 = row0 + mf * 16 + kg * 4;
        u16 pk0 = f2bf(1.f / (1.f + __expf(-acc[mf][0])));
        u16 pk1 = f2bf(1.f / (1.f + __expf(-acc[mf][1])));
        u16 pk2 = f2bf(1.f / (1.f + __expf(-acc[mf][2])));
        u16 pk3 = f2bf(1.f / (1.f + __expf(-acc[mf][3])));
        u32* dst = reinterpret_cast<u32*>(g_out + ((size_t)s * 512 + colj) * 256 + hcrow0);
        dst[0] = (u32)pk0 | ((u32)pk1 << 16);
        dst[1] = (u32)pk2 | ((u32)pk3 << 16);
      }
    }
  }
}

// ---------------------------------------------------------------- Kernel 3
// grid (64, 4, 8): nt, mt, h. Block 256 = 4 waves (2x2), 128x128 tile, BK=32.
__global__ __launch_bounds__(256) void k3_einsum(
    const u16* __restrict__ w_buf, const u16* __restrict__ vT,
    float* __restrict__ O)
{
  const int nt = blockIdx.x, mt = blockIdx.y, h = blockIdx.z;
  const int t = threadIdx.x, lane = t & 63, wid = t >> 6;
  const int Mbase = mt * 128, Nbase = nt * 128;
  __shared__ u16 at[128 * 32];
  __shared__ u16 btl[128 * 32];
  const u16* Ag = w_buf + (size_t)h * 512 * 512;
  const u16* Bg = vT + (size_t)h * 8192 * 512;
  const int wr = wid >> 1, wc = wid & 1;
  const int r16 = lane & 15, kg = lane >> 4;
  const int srow = lane >> 2, scol = (lane & 3) * 8;
  f32x4 acc[4][4];
#pragma unroll
  for (int ii = 0; ii < 4; ++ii)
#pragma unroll
    for (int jj2 = 0; jj2 < 4; ++jj2) acc[ii][jj2] = (f32x4){0.f, 0.f, 0.f, 0.f};

  for (int kt = 0; kt < 16; ++kt) {
    const int k0 = kt * 32;
#pragma unroll
    for (int q = 0; q < 2; ++q) {
      const int rbase = wid * 32 + q * 16;  // wave-uniform
      GLD_LDS16(Ag + (size_t)(Mbase + rbase + srow) * 512 + k0 + scol, at + rbase * 32);
      GLD_LDS16(Bg + (size_t)(Nbase + rbase + srow) * 512 + k0 + scol, btl + rbase * 32);
    }
    __syncthreads();
    bf16x8 av[4], bv[4];
#pragma unroll
    for (int mf = 0; mf < 4; ++mf)
      av[mf] = *reinterpret_cast<const bf16x8*>(&at[(wr * 64 + mf * 16 + r16) * 32 + kg * 8]);
#pragma unroll
    for (int nf = 0; nf < 4; ++nf)
      bv[nf] = *reinterpret_cast<const bf16x8*>(&btl[(wc * 64 + nf * 16 + r16) * 32 + kg * 8]);
#pragma unroll
    for (int mf = 0; mf < 4; ++mf)
#pragma unroll
      for (int nf = 0; nf < 4; ++nf)
        acc[mf][nf] = __builtin_amdgcn_mfma_f32_16x16x32_bf16(av[mf], bv[nf], acc[mf][nf], 0, 0, 0);
    __syncthreads();
  }
  float* Obase = O + (size_t)h * 512 * 8192;
#pragma unroll
  for (int mf = 0; mf < 4; ++mf) {
#pragma unroll
    for (int r = 0; r < 4; ++r) {
      const int irow = Mbase + wr * 64 + mf * 16 + kg * 4 + r;
#pragma unroll
      for (int nf = 0; nf < 4; ++nf) {
        const int n = Nbase + wc * 64 + nf * 16 + r16;
        Obase[(size_t)irow * 8192 + n] = acc[mf][nf][r];
      }
    }
  }
}

// ---------------------------------------------------------------- Kernel 4
// grid (4, 512): st, i. Block 256 = 4 waves. M=64 (s), N=64 (cm), K=256 (hc).
__global__ __launch_bounds__(256) void k4_out(
    const float* __restrict__ O, const u16* __restrict__ g_buf,
    const float* __restrict__ W_o, float* __restrict__ out)
{
  const int st = blockIdx.x, i = blockIdx.y;
  const int s0 = st * 64;
  const int t = threadIdx.x, lane = t & 63, wid = t >> 6;
  __shared__ u16 Al[64][264];
  __shared__ u16 Wl[64][264];
  for (int idx = t; idx < 64 * 256; idx += 256) {
    int row = idx >> 8, col = idx & 255;
    Wl[row][col] = f2bf(W_o[idx]);
  }
  {
    const int hh = t >> 5, cc = t & 31;
    const float* Op = O + ((size_t)hh * 512 + i) * 8192 + (size_t)s0 * 32 + cc;
    const u16* gp = g_buf + ((size_t)s0 * 512 + i) * 256 + t;
#pragma unroll 4
    for (int sl = 0; sl < 64; ++sl) {
      float ov = Op[sl * 32];
      float gv = bf2f(gp[sl * 131072]);   // stride 512*256
      Al[sl][t] = f2bf(ov * gv);
    }
  }
  __syncthreads();

  const int r16 = lane & 15, kg = lane >> 4;
  f32x4 acc[4];
#pragma unroll
  for (int nf = 0; nf < 4; ++nf) acc[nf] = (f32x4){0.f, 0.f, 0.f, 0.f};
#pragma unroll
  for (int kf = 0; kf < 8; ++kf) {
    bf16x8 a = *reinterpret_cast<const bf16x8*>(&Al[wid * 16 + r16][kf * 32 + kg * 8]);
#pragma unroll
    for (int nf = 0; nf < 4; ++nf) {
      bf16x8 b = *reinterpret_cast<const bf16x8*>(&Wl[nf * 16 + r16][kf * 32 + kg * 8]);
      acc[nf] = __builtin_amdgcn_mfma_f32_16x16x32_bf16(a, b, acc[nf], 0, 0, 0);
    }
  }
#pragma unroll
  for (int nf = 0; nf < 4; ++nf) {
#pragma unroll
    for (int r = 0; r < 4; ++r) {
      int srow = wid * 16 + kg * 4 + r;
      int cm = nf * 16 + r16;
      out[((size_t)(s0 + srow) * 512 + i) * 64 + cm] = acc[nf][r];
    }
  }
}

// ---------------------------------------------------------------- launcher
extern "C" void kernel_launch(void* const* d_in, const int* in_sizes, int n_in,
                              void* d_out, int out_size, void* d_ws, size_t ws_size,
                              hipStream_t stream) {
  const float* m        = (const float*)d_in[0];
  const float* z        = (const float*)d_in[1];
  const float* msa_mask = (const float*)d_in[2];
  const float* z_mask   = (const float*)d_in[3];
  const float* ln_m_g   = (const float*)d_in[4];
  const float* ln_m_b   = (const float*)d_in[5];
  const float* W_v      = (const float*)d_in[6];
  const float* W_g      = (const float*)d_in[7];
  const float* ln_z_g   = (const float*)d_in[8];
  const float* ln_z_b   = (const float*)d_in[9];
  const float* W_b      = (const float*)d_in[10];
  const float* W_o      = (const float*)d_in[11];
  float* out = (float*)d_out;

  char* ws = (char*)d_ws;
  u16*   w_buf = (u16*)(ws);                                   //   4 MiB: [8][512][512] bf16
  u16*   vT    = (u16*)(ws + (4u << 20));                      //  64 MiB: [8][8192][512] bf16
  u16*   g_buf = (u16*)(ws + (68u << 20));                     //  64 MiB: [256][512][256] bf16
  float* O     = (float*)(ws + (132u << 20));                  // 128 MiB: [8][512][8192] f32

  k1_bias_softmax<<<dim3(512), dim3(256), 0, stream>>>(z, z_mask, ln_z_g, ln_z_b, W_b, w_buf);
  k2_vg<<<dim3(4, 256), dim3(256), 0, stream>>>(m, msa_mask, ln_m_g, ln_m_b, W_v, W_g, vT, g_buf);
  k3_einsum<<<dim3(64, 4, 8), dim3(256), 0, stream>>>(w_buf, vT, O);
  k4_out<<<dim3(4, 512), dim3(256), 0, stream>>>(O, g_buf, W_o, out);
}

// Round 2
// 379.799 us; speedup vs baseline: 1.1543x; 1.1543x over previous
//
#include <hip/hip_runtime.h>
#include <stdint.h>

// Pipeline (all MFMA inputs bf16, accum f32):
//  k0 : W_v,W_g,W_o,W_b -> bf16 (Wvg[512][64], Wo[64][256], Wb[16][128])
//  k1a: bbuf[h][i][j] = LN(z[i,j,:]).Wb[h,:] + INF*(zmask-1)      (f32, MFMA)
//  k1b: wbuf[h][i][j] = softmax_j(bbuf)                            (bf16)
//  k2 : vT[h][s*32+c][j] = (LN(m[s,j,:]).Wv[hc,:])*mask[s,j]       (bf16, LDS-transposed)
//       gbuf[s][i][hc]   = sigmoid(LN(m[s,i,:]).Wg[hc,:])          (bf16)
//  k3 : O2[i][s][hc] = sum_j wbuf[h][i][j]*vT[h][s*32+c][j]        (bf16, swizzled staging)
//  k4 : out[s][i][cm] = sum_hc (gbuf*O2)[s,i,hc] * Wo[cm][hc]      (f32)

typedef unsigned short u16;
typedef unsigned int u32;
typedef __attribute__((ext_vector_type(4))) float f32x4;
typedef __attribute__((ext_vector_type(8))) short bf16x8;

__device__ __forceinline__ u16 f2bf(float f) {
  u32 u = __float_as_uint(f);
  u = u + 0x7fffu + ((u >> 16) & 1u);
  return (u16)(u >> 16);
}
__device__ __forceinline__ float bf2f(u16 h) { return __uint_as_float(((u32)h) << 16); }

__device__ __forceinline__ bf16x8 pack8(const float* f) {
  bf16x8 r;
#pragma unroll
  for (int e = 0; e < 8; ++e) r[e] = (short)f2bf(f[e]);
  return r;
}

#define GLD_LDS16(gp, lp) __builtin_amdgcn_global_load_lds(                 \
    (__attribute__((address_space(1))) const void*)(gp),                    \
    (__attribute__((address_space(3))) void*)(lp), 16, 0, 0)

// ---------------------------------------------------------------- k0
__global__ __launch_bounds__(256) void k0_convert(
    const float* __restrict__ W_v, const float* __restrict__ W_g,
    const float* __restrict__ W_o, const float* __restrict__ W_b,
    u16* __restrict__ Wvg, u16* __restrict__ Wo, u16* __restrict__ Wb)
{
  int id = blockIdx.x * 256 + threadIdx.x;
  if (id < 32768) {
    int row = id >> 6, col = id & 63;
    float v = (row < 256) ? W_v[row * 64 + col] : W_g[(row - 256) * 64 + col];
    Wvg[id] = f2bf(v);
  } else if (id < 49152) {
    int k = id - 32768;
    Wo[k] = f2bf(W_o[k]);
  } else if (id < 51200) {
    int k = id - 49152;
    Wb[k] = (k < 1024) ? f2bf(W_b[k]) : (u16)0;
  }
}

// ---------------------------------------------------------------- k1a
// grid (4, 512): (j-chunk, i). block 256 = 4 waves.
__global__ __launch_bounds__(256) void k1a_bias(
    const float* __restrict__ z, const float* __restrict__ z_mask,
    const float* __restrict__ gzp, const float* __restrict__ bzp,
    const u16* __restrict__ Wb, float* __restrict__ bbuf)
{
  const int jc = blockIdx.x, i = blockIdx.y;
  const int j0 = jc * 128;
  const int t = threadIdx.x, lane = t & 63, wid = t >> 6;
  const int r16 = lane & 15, kg = lane >> 4;
  __shared__ char zns[32768];            // zn[128 rows][256B] bf16, XOR(row&7) swizzled
  __shared__ float bl[8][132];
  __shared__ float gz[128], bz[128];
  if (t < 128) { gz[t] = gzp[t]; bz[t] = bzp[t]; }
  __syncthreads();

  // LayerNorm: 2 passes, 4 threads per 128-f32 row
#pragma unroll
  for (int rr = 0; rr < 2; ++rr) {
    const int row = rr * 64 + (t >> 2), part = t & 3;
    const float* zr = z + ((size_t)i * 512 + j0 + row) * 128 + part * 32;
    f32x4 v[8];
    float s = 0.f, sq = 0.f;
#pragma unroll
    for (int q = 0; q < 8; ++q) {
      v[q] = *reinterpret_cast<const f32x4*>(zr + 4 * q);
#pragma unroll
      for (int e = 0; e < 4; ++e) { s += v[q][e]; sq += v[q][e] * v[q][e]; }
    }
    s += __shfl_xor(s, 1); s += __shfl_xor(s, 2);
    sq += __shfl_xor(sq, 1); sq += __shfl_xor(sq, 2);
    float mean = s * (1.f / 128.f);
    float rstd = rsqrtf(sq * (1.f / 128.f) - mean * mean + 1e-5f);
#pragma unroll
    for (int uu = 0; uu < 4; ++uu) {
      float tmp[8];
#pragma unroll
      for (int e = 0; e < 8; ++e) {
        int k = part * 32 + uu * 8 + e;
        tmp[e] = (v[uu * 2 + (e >> 2)][e & 3] - mean) * rstd * gz[k] + bz[k];
      }
      int byte = (row * 256 + part * 64 + uu * 16) ^ ((row & 7) << 4);
      *reinterpret_cast<bf16x8*>(zns + byte) = pack8(tmp);
    }
  }
  __syncthreads();

  // MFMA: [128 j] x [16 h (8 valid)] x K=128
  bf16x8 av[2][4], bw[4];
#pragma unroll
  for (int mf = 0; mf < 2; ++mf)
#pragma unroll
    for (int kf = 0; kf < 4; ++kf) {
      int row = wid * 32 + mf * 16 + r16;
      int byte = (row * 256 + (kf * 4 + kg) * 16) ^ ((row & 7) << 4);
      av[mf][kf] = *reinterpret_cast<const bf16x8*>(zns + byte);
    }
#pragma unroll
  for (int kf = 0; kf < 4; ++kf)
    bw[kf] = *reinterpret_cast<const bf16x8*>(Wb + r16 * 128 + kf * 32 + kg * 8);
  f32x4 acc[2];
  acc[0] = (f32x4){0.f, 0.f, 0.f, 0.f}; acc[1] = acc[0];
#pragma unroll
  for (int mf = 0; mf < 2; ++mf)
#pragma unroll
    for (int kf = 0; kf < 4; ++kf)
      acc[mf] = __builtin_amdgcn_mfma_f32_16x16x32_bf16(av[mf][kf], bw[kf], acc[mf], 0, 0, 0);
  if (r16 < 8) {
#pragma unroll
    for (int mf = 0; mf < 2; ++mf)
#pragma unroll
      for (int r = 0; r < 4; ++r)
        bl[r16][wid * 32 + mf * 16 + kg * 4 + r] = acc[mf][r];
  }
  __syncthreads();

  // mask + store f32
  {
    const int h = t >> 5, jj = t & 31;
    f32x4 bv = *reinterpret_cast<const f32x4*>(&bl[h][jj * 4]);
    f32x4 zm = *reinterpret_cast<const f32x4*>(z_mask + (size_t)i * 512 + j0 + jj * 4);
#pragma unroll
    for (int e = 0; e < 4; ++e) bv[e] += 1e8f * (zm[e] - 1.f);
    *reinterpret_cast<f32x4*>(bbuf + ((size_t)h * 512 + i) * 512 + j0 + jj * 4) = bv;
  }
}

// ---------------------------------------------------------------- k1b
// grid 1024, block 256 = 4 waves; one wave per (h,i) row of 512.
__global__ __launch_bounds__(256) void k1b_softmax(
    const float* __restrict__ bbuf, u16* __restrict__ wbuf)
{
  const int t = threadIdx.x, lane = t & 63, wid = t >> 6;
  const size_t row = (size_t)blockIdx.x * 4 + wid;
  const float* src = bbuf + row * 512 + lane * 8;
  f32x4 a = *reinterpret_cast<const f32x4*>(src);
  f32x4 b = *reinterpret_cast<const f32x4*>(src + 4);
  float vals[8];
#pragma unroll
  for (int e = 0; e < 4; ++e) { vals[e] = a[e]; vals[4 + e] = b[e]; }
  float mx = vals[0];
#pragma unroll
  for (int e = 1; e < 8; ++e) mx = fmaxf(mx, vals[e]);
#pragma unroll
  for (int m = 1; m < 64; m <<= 1) mx = fmaxf(mx, __shfl_xor(mx, m));
  float sum = 0.f;
#pragma unroll
  for (int e = 0; e < 8; ++e) { vals[e] = __expf(vals[e] - mx); sum += vals[e]; }
#pragma unroll
  for (int m = 1; m < 64; m <<= 1) sum += __shfl_xor(sum, m);
  float inv = 1.f / sum;
  bf16x8 o;
#pragma unroll
  for (int e = 0; e < 8; ++e) o[e] = (short)f2bf(vals[e] * inv);
  *reinterpret_cast<bf16x8*>(wbuf + row * 512 + lane * 8) = o;
}

// ---------------------------------------------------------------- k2
// grid (4, 256): (j-chunk, s). block 512 = 8 waves.
__global__ __launch_bounds__(512) void k2_vg(
    const float* __restrict__ m, const float* __restrict__ msa_mask,
    const float* __restrict__ gmp, const float* __restrict__ bmp,
    const u16* __restrict__ Wvg, u16* __restrict__ vT, u16* __restrict__ gbuf)
{
  const int jt = blockIdx.x, s = blockIdx.y;
  const int j0 = jt * 128;
  const int t = threadIdx.x, lane = t & 63, wid = t >> 6;
  const int r16 = lane & 15, kg = lane >> 4;
  __shared__ char smem[65536];   // phase1: bt[128 rows][128B] swz; phase2: T[256 hc][256B] swz
  __shared__ float maskl[128], gk[64], bk[64];
  if (t < 64) gk[t] = gmp[t];
  else if (t < 128) bk[t - 64] = bmp[t - 64];
  if (t < 128) maskl[t] = msa_mask[(size_t)s * 512 + j0 + t];
  __syncthreads();

  // LayerNorm: 4 threads per 64-f32 row, 128 rows
  {
    const int row = t >> 2, part = t & 3;
    const float* mr = m + ((size_t)s * 512 + j0 + row) * 64 + part * 16;
    f32x4 v[4];
    float sm = 0.f, sq = 0.f;
#pragma unroll
    for (int q = 0; q < 4; ++q) {
      v[q] = *reinterpret_cast<const f32x4*>(mr + 4 * q);
#pragma unroll
      for (int e = 0; e < 4; ++e) { sm += v[q][e]; sq += v[q][e] * v[q][e]; }
    }
    sm += __shfl_xor(sm, 1); sm += __shfl_xor(sm, 2);
    sq += __shfl_xor(sq, 1); sq += __shfl_xor(sq, 2);
    float mean = sm * (1.f / 64.f);
    float rstd = rsqrtf(sq * (1.f / 64.f) - mean * mean + 1e-5f);
#pragma unroll
    for (int uu = 0; uu < 2; ++uu) {
      float tmp[8];
#pragma unroll
      for (int e = 0; e < 8; ++e) {
        int k = part * 16 + uu * 8 + e;
        tmp[e] = (v[uu * 2 + (e >> 2)][e & 3] - mean) * rstd * gk[k] + bk[k];
      }
      int byte = (row * 128 + part * 32 + uu * 16) ^ ((row & 7) << 4);
      *reinterpret_cast<bf16x8*>(smem + byte) = pack8(tmp);
    }
  }
  __syncthreads();

  const int jh = wid & 1, hcq0 = wid >> 1;
  bf16x8 av[4][2];
#pragma unroll
  for (int mf = 0; mf < 4; ++mf)
#pragma unroll
    for (int kf = 0; kf < 2; ++kf) {
      int row = jh * 64 + mf * 16 + r16;
      int byte = (row * 128 + (kf * 4 + kg) * 16) ^ ((row & 7) << 4);
      av[mf][kf] = *reinterpret_cast<const bf16x8*>(smem + byte);
    }
  __syncthreads();   // bt reads done; T may overwrite

#pragma unroll
  for (int rep = 0; rep < 2; ++rep) {
    const int hcq = hcq0 + rep * 4;
    bf16x8 bv[4][2];
#pragma unroll
    for (int nf = 0; nf < 4; ++nf)
#pragma unroll
      for (int kf = 0; kf < 2; ++kf)
        bv[nf][kf] = *reinterpret_cast<const bf16x8*>(
            Wvg + (hcq * 64 + nf * 16 + r16) * 64 + kf * 32 + kg * 8);
    f32x4 acc[4][4];
#pragma unroll
    for (int mf = 0; mf < 4; ++mf)
#pragma unroll
      for (int nf = 0; nf < 4; ++nf) acc[mf][nf] = (f32x4){0.f, 0.f, 0.f, 0.f};
#pragma unroll
    for (int mf = 0; mf < 4; ++mf)
#pragma unroll
      for (int nf = 0; nf < 4; ++nf)
#pragma unroll
        for (int kf = 0; kf < 2; ++kf)
          acc[mf][nf] = __builtin_amdgcn_mfma_f32_16x16x32_bf16(av[mf][kf], bv[nf][kf], acc[mf][nf], 0, 0, 0);

    if (rep == 0) {
      // v: mask, transpose through LDS T[hc][j]
#pragma unroll
      for (int mf = 0; mf < 4; ++mf)
#pragma unroll
        for (int nf = 0; nf < 4; ++nf)
#pragma unroll
          for (int r = 0; r < 4; ++r) {
            int j = jh * 64 + mf * 16 + kg * 4 + r;
            int hc = hcq * 64 + nf * 16 + r16;
            float val = acc[mf][nf][r] * maskl[j];
            int byte = (hc * 256 + j * 2) ^ ((hc & 7) << 4);
            *reinterpret_cast<u16*>(smem + byte) = f2bf(val);
          }
      __syncthreads();
      // coalesced vT store: 4096 16B units
#pragma unroll
      for (int it = 0; it < 8; ++it) {
        int u = it * 512 + t;
        int hc = u >> 4, sub = u & 15;
        int byte = (hc * 256 + sub * 16) ^ ((hc & 7) << 4);
        bf16x8 rv = *reinterpret_cast<const bf16x8*>(smem + byte);
        int h = hc >> 5, c = hc & 31;
        *reinterpret_cast<bf16x8*>(
            vT + (((size_t)h * 8192 + s * 32 + c) * 512 + j0 + sub * 8)) = rv;
      }
    } else {
      // g: sigmoid, direct stores (L2 merges 32B row chunks)
#pragma unroll
      for (int mf = 0; mf < 4; ++mf)
#pragma unroll
        for (int nf = 0; nf < 4; ++nf)
#pragma unroll
          for (int r = 0; r < 4; ++r) {
            int j = jh * 64 + mf * 16 + kg * 4 + r;
            int hc = hcq0 * 64 + nf * 16 + r16;
            float val = 1.f / (1.f + __expf(-acc[mf][nf][r]));
            gbuf[((size_t)s * 512 + j0 + j) * 256 + hc] = f2bf(val);
          }
    }
  }
}

// ---------------------------------------------------------------- k3
// grid (64, 4, 8): (nt, mt, h). block 256 = 4 waves (2x2). 128x128 tile, BK=64.
__global__ __launch_bounds__(256) void k3_einsum(
    const u16* __restrict__ wbuf, const u16* __restrict__ vT, u16* __restrict__ O2)
{
  const int nt = blockIdx.x, mt = blockIdx.y, h = blockIdx.z;
  const int t = threadIdx.x, lane = t & 63, wid = t >> 6;
  const int Mbase = mt * 128, Nbase = nt * 128;
  __shared__ char smem[32768];     // at[128][128B] swz | btl[128][128B] swz ; epilogue Tep
  const u16* Ag = wbuf + (size_t)h * 262144;
  const u16* Bg = vT + (size_t)h * 4194304;
  const int wr = wid >> 1, wc = wid & 1;
  const int r16 = lane & 15, kg = lane >> 4;
  const int lrow = lane >> 3, lslot = lane & 7;
  f32x4 acc[4][4];
#pragma unroll
  for (int a = 0; a < 4; ++a)
#pragma unroll
    for (int b = 0; b < 4; ++b) acc[a][b] = (f32x4){0.f, 0.f, 0.f, 0.f};

  for (int kt = 0; kt < 8; ++kt) {
    const int k0 = kt * 64;
#pragma unroll
    for (int q = 0; q < 4; ++q) {
      const int rb = wid * 32 + q * 8;
      const int pr = rb + lrow;
      const int su = (lslot ^ (pr & 7)) * 8;   // pre-swizzled source column
      GLD_LDS16(Ag + (size_t)(Mbase + pr) * 512 + k0 + su, (u16*)smem + rb * 64);
      GLD_LDS16(Bg + (size_t)(Nbase + pr) * 512 + k0 + su, (u16*)(smem + 16384) + rb * 64);
    }
    __syncthreads();
    bf16x8 av[4][2], bv[4][2];
#pragma unroll
    for (int mf = 0; mf < 4; ++mf)
#pragma unroll
      for (int kf = 0; kf < 2; ++kf) {
        int rowA = wr * 64 + mf * 16 + r16;
        int byteA = (rowA * 128 + (kf * 4 + kg) * 16) ^ ((rowA & 7) << 4);
        av[mf][kf] = *reinterpret_cast<const bf16x8*>(smem + byteA);
        int rowB = wc * 64 + mf * 16 + r16;
        int byteB = (rowB * 128 + (kf * 4 + kg) * 16) ^ ((rowB & 7) << 4);
        bv[mf][kf] = *reinterpret_cast<const bf16x8*>(smem + 16384 + byteB);
      }
#pragma unroll
    for (int mf = 0; mf < 4; ++mf)
#pragma unroll
      for (int nf = 0; nf < 4; ++nf)
#pragma unroll
        for (int kf = 0; kf < 2; ++kf)
          acc[mf][nf] = __builtin_amdgcn_mfma_f32_16x16x32_bf16(av[mf][kf], bv[nf][kf], acc[mf][nf], 0, 0, 0);
    __syncthreads();
  }

  // epilogue: acc -> bf16 Tep[i 128][sc 128] -> coalesced O2[i][s][hc]
  u16* Tep = (u16*)smem;
#pragma unroll
  for (int mf = 0; mf < 4; ++mf)
#pragma unroll
    for (int nf = 0; nf < 4; ++nf)
#pragma unroll
      for (int r = 0; r < 4; ++r) {
        int il = wr * 64 + mf * 16 + kg * 4 + r;
        int sc = wc * 64 + nf * 16 + r16;
        Tep[il * 128 + sc] = f2bf(acc[mf][nf][r]);
      }
  __syncthreads();
#pragma unroll
  for (int it = 0; it < 8; ++it) {
    int u = it * 256 + t;
    int il = u >> 4, sub = u & 15;
    bf16x8 rv = *reinterpret_cast<const bf16x8*>(Tep + il * 128 + sub * 8);
    int scg = Nbase + sub * 8;
    int sI = scg >> 5, c = scg & 31;
    *reinterpret_cast<bf16x8*>(
        O2 + (((size_t)(Mbase + il) * 256 + sI) * 256 + h * 32 + c)) = rv;
  }
}

// ---------------------------------------------------------------- k4
// grid (4, 512): (s-tile, i). block 256 = 4 waves. M=64(s) N=64(cm) K=256(hc).
__global__ __launch_bounds__(256) void k4_out(
    const u16* __restrict__ O2, const u16* __restrict__ gbuf,
    const u16* __restrict__ Wo, float* __restrict__ out)
{
  const int st = blockIdx.x, i = blockIdx.y;
  const int s0 = st * 64;
  const int t = threadIdx.x, lane = t & 63, wid = t >> 6;
  const int r16 = lane & 15, kg = lane >> 4;
  __shared__ u16 Al[64][264];
  __shared__ u16 Wl[64][264];
#pragma unroll
  for (int it = 0; it < 8; ++it) {
    int u = it * 256 + t, row = u >> 5, sub = u & 31;
    *reinterpret_cast<bf16x8*>(&Wl[row][sub * 8]) =
        *reinterpret_cast<const bf16x8*>(Wo + row * 256 + sub * 8);
  }
  {
    const int sl = t >> 2, hc0 = (t & 3) * 64;
    const u16* Op = O2 + ((size_t)i * 256 + s0 + sl) * 256 + hc0;
    const u16* gp = gbuf + ((size_t)(s0 + sl) * 512 + i) * 256 + hc0;
#pragma unroll
    for (int uu = 0; uu < 8; ++uu) {
      bf16x8 ov = *reinterpret_cast<const bf16x8*>(Op + uu * 8);
      bf16x8 gv = *reinterpret_cast<const bf16x8*>(gp + uu * 8);
      bf16x8 r;
#pragma unroll
      for (int e = 0; e < 8; ++e) r[e] = (short)f2bf(bf2f((u16)ov[e]) * bf2f((u16)gv[e]));
      *reinterpret_cast<bf16x8*>(&Al[sl][hc0 + uu * 8]) = r;
    }
  }
  __syncthreads();

  f32x4 acc[4];
#pragma unroll
  for (int nf = 0; nf < 4; ++nf) acc[nf] = (f32x4){0.f, 0.f, 0.f, 0.f};
#pragma unroll
  for (int kf = 0; kf < 8; ++kf) {
    bf16x8 a = *reinterpret_cast<const bf16x8*>(&Al[wid * 16 + r16][kf * 32 + kg * 8]);
#pragma unroll
    for (int nf = 0; nf < 4; ++nf) {
      bf16x8 b = *reinterpret_cast<const bf16x8*>(&Wl[nf * 16 + r16][kf * 32 + kg * 8]);
      acc[nf] = __builtin_amdgcn_mfma_f32_16x16x32_bf16(a, b, acc[nf], 0, 0, 0);
    }
  }
#pragma unroll
  for (int nf = 0; nf < 4; ++nf)
#pragma unroll
    for (int r = 0; r < 4; ++r)
      out[((size_t)(s0 + wid * 16 + kg * 4 + r) * 512 + i) * 64 + nf * 16 + r16] = acc[nf][r];
}

// ---------------------------------------------------------------- launcher
extern "C" void kernel_launch(void* const* d_in, const int* in_sizes, int n_in,
                              void* d_out, int out_size, void* d_ws, size_t ws_size,
                              hipStream_t stream) {
  const float* m        = (const float*)d_in[0];
  const float* z        = (const float*)d_in[1];
  const float* msa_mask = (const float*)d_in[2];
  const float* z_mask   = (const float*)d_in[3];
  const float* ln_m_g   = (const float*)d_in[4];
  const float* ln_m_b   = (const float*)d_in[5];
  const float* W_v      = (const float*)d_in[6];
  const float* W_g      = (const float*)d_in[7];
  const float* ln_z_g   = (const float*)d_in[8];
  const float* ln_z_b   = (const float*)d_in[9];
  const float* W_b      = (const float*)d_in[10];
  const float* W_o      = (const float*)d_in[11];
  float* out = (float*)d_out;

  char* ws = (char*)d_ws;
  u16*   Wvg  = (u16*)(ws);                 //  64 KiB [512][64]
  u16*   Wo   = (u16*)(ws + 65536);         //  32 KiB [64][256]
  u16*   Wb   = (u16*)(ws + 98304);         //   4 KiB [16][128]
  float* bbuf = (float*)(ws + (1u  << 20)); //   8 MiB [8][512][512]
  u16*   wbuf = (u16*)  (ws + (9u  << 20)); //   4 MiB [8][512][512]
  u16*   vT   = (u16*)  (ws + (16u << 20)); //  64 MiB [8][8192][512]
  u16*   gbuf = (u16*)  (ws + (80u << 20)); //  64 MiB [256][512][256]
  u16*   O2   = (u16*)  (ws + (144u << 20));//  64 MiB [512][256][256]

  k0_convert<<<200, 256, 0, stream>>>(W_v, W_g, W_o, W_b, Wvg, Wo, Wb);
  k1a_bias<<<dim3(4, 512), 256, 0, stream>>>(z, z_mask, ln_z_g, ln_z_b, Wb, bbuf);
  k1b_softmax<<<1024, 256, 0, stream>>>(bbuf, wbuf);
  k2_vg<<<dim3(4, 256), 512, 0, stream>>>(m, msa_mask, ln_m_g, ln_m_b, Wvg, vT, gbuf);
  k3_einsum<<<dim3(64, 4, 8), 256, 0, stream>>>(wbuf, vT, O2);
  k4_out<<<dim3(4, 512), 256, 0, stream>>>(O2, gbuf, Wo, out);
}